// Round 1
// 106.636 us; speedup vs baseline: 1.0064x; 1.0064x over previous
//
#include <hip/hip_runtime.h>

// GraphAttentionLayer: B=2, N=512, D=256, H=4, HD=64, slope=0.2
// Inputs f32, outputs f32 = concat(h_prime [B,N,256], e [B,N,N,4]).
// lrelu(x) = 0.6x + 0.4|x|; hk-dot term is j-constant -> cancels in softmax:
// score = 0.6*sum_f hq*a + 0.4*sum_f |hq+hk|*a.
// R16: (a) proj restructured 16x128 -> 32x64 tile (still 2r x 4c/thread):
// every wave now touches 64 block-cols of w instead of 128, halving L1 w
// traffic (196MB -> 98MB, ~5us -> ~2.5us L1-bound); accumulators switched to
// packed v_pk_fma_f32 halving VALU issue. (b) attn: e-store folded into the
// softmax phase (store from registers), dropping the separate e-write pass
// and its 8 ds_read/thread. Top-5 rocprof rows are all 42us 256MiB harness
// poison fills (>=1 inside the timed window) -> controllable budget is the
// proj+attn sum only; predicted dur 107.3 -> ~100-104.

#define NB 2
#define NN 512
#define DD 256
#define NH 4
#define HDIM 64

typedef __attribute__((ext_vector_type(2))) float f32x2;

__device__ __forceinline__ f32x2 pk_fma(f32x2 a, f32x2 b, f32x2 c) {
    return __builtin_elementwise_fma(a, b, c);
}
__device__ __forceinline__ f32x2 pk_abs(f32x2 t) {
    return __builtin_elementwise_max(t, -t);     // v_pk_max_f32 with neg mod
}

// ---------------- proj: register-blocked GEMM, 32 rows x 64 cols/block -----
// thread = 2 rows x 4 cols, packed FMA. m==0 (query) writes transposed:
// hqT[((b*NH+h)*HDIM+f)*NN + j]. BN=64 aligns with HDIM -> one head/block.
__global__ __launch_bounds__(256, 4) void proj_kernel(
    const float* __restrict__ q, const float* __restrict__ kin, const float* __restrict__ vin,
    const float* __restrict__ wq, const float* __restrict__ bq,
    const float* __restrict__ wv, const float* __restrict__ bv,
    float* __restrict__ hqt, float* __restrict__ hk, float* __restrict__ hv)
{
    const int m = blockIdx.z;
    const float* x    = (m == 0) ? q  : (m == 1) ? kin : vin;
    const float* w    = (m == 2) ? wv : wq;
    const float* bias = (m == 2) ? bv : bq;
    float* out        = (m == 0) ? hqt : (m == 1) ? hk : hv;

    const int r0 = blockIdx.x * 32;
    const int cb = blockIdx.y * 64;
    const int t  = threadIdx.x;

    __shared__ float xs[32][DD + 4];              // 32.5 KB

    #pragma unroll
    for (int p = 0; p < 8; ++p) {
        const int idx = t + 256 * p;              // 0..2047 float4 slots
        const int row = idx >> 6;
        const int kc  = idx & 63;
        const float4 v = *reinterpret_cast<const float4*>(&x[(size_t)(r0 + row) * DD + kc * 4]);
        *reinterpret_cast<float4*>(&xs[row][kc * 4]) = v;
    }
    __syncthreads();

    const int rp2 = (t >> 4) * 2;                 // row pair 0,2,..,30
    const int c0  = (t & 15) * 4;                 // col quad within 64

    const float4 b4 = *reinterpret_cast<const float4*>(&bias[cb + c0]);
    f32x2 acc[2][2];
    #pragma unroll
    for (int rr = 0; rr < 2; ++rr) { acc[rr][0] = f32x2{b4.x, b4.y}; acc[rr][1] = f32x2{b4.z, b4.w}; }

    for (int kt = 0; kt < DD; kt += 4) {
        const float4 a0 = *reinterpret_cast<const float4*>(&xs[rp2][kt]);
        const float4 a1 = *reinterpret_cast<const float4*>(&xs[rp2 + 1][kt]);
        const float xa0[4] = {a0.x, a0.y, a0.z, a0.w};
        const float xa1[4] = {a1.x, a1.y, a1.z, a1.w};
        #pragma unroll
        for (int kk = 0; kk < 4; ++kk) {
            const float4 w4 = *reinterpret_cast<const float4*>(&w[(size_t)(kt + kk) * DD + cb + c0]);
            const f32x2 wlo = {w4.x, w4.y}, whi = {w4.z, w4.w};
            const f32x2 x0 = {xa0[kk], xa0[kk]};
            const f32x2 x1 = {xa1[kk], xa1[kk]};
            acc[0][0] = pk_fma(x0, wlo, acc[0][0]);
            acc[0][1] = pk_fma(x0, whi, acc[0][1]);
            acc[1][0] = pk_fma(x1, wlo, acc[1][0]);
            acc[1][1] = pk_fma(x1, whi, acc[1][1]);
        }
    }
    if (m == 0) {                                 // transposed scatter store
        const int hh = cb >> 6;                   // BN==HDIM -> uniform head
        #pragma unroll
        for (int rr = 0; rr < 2; ++rr) {
            const int rg = r0 + rp2 + rr;
            const int bb = rg >> 9, j = rg & 511;
            const float v4[4] = {acc[rr][0].x, acc[rr][0].y, acc[rr][1].x, acc[rr][1].y};
            #pragma unroll
            for (int cc = 0; cc < 4; ++cc)
                out[(((size_t)(bb * NH) + hh) * HDIM + (c0 + cc)) * NN + j] = v4[cc];
        }
    } else {
        #pragma unroll
        for (int rr = 0; rr < 2; ++rr) {
            const int rg = r0 + rp2 + rr;
            float4 o; o.x = acc[rr][0].x; o.y = acc[rr][0].y; o.z = acc[rr][1].x; o.w = acc[rr][1].y;
            *reinterpret_cast<float4*>(&out[(size_t)rg * DD + cb + c0]) = o;
        }
    }
}

// ------ attn: block = (b, 8 i-rows, one head), 512 threads, 8 waves --------
__global__ __launch_bounds__(512, 4) void attn_kernel(
    const float* __restrict__ hqt, const float* __restrict__ hk, const float* __restrict__ hv,
    const float* __restrict__ a, float* __restrict__ out_hp, float* __restrict__ out_e)
{
    const int t    = threadIdx.x;
    // XCD swizzle: h-blocks of one (b,i-tile) are 128 apart (≡ mod 8 -> same XCD)
    const int h    = blockIdx.x >> 7;
    const int rest = blockIdx.x & 127;
    const int b    = rest >> 6;
    const int i0   = (rest & 63) * 8;

    __shared__ float s[8][NN + 8];                // [ii][j]  16.6 KB
    __shared__ float part[8][8][HDIM];            // [w][ii][col] 16 KB

    const float* hk0 = hk + ((size_t)(b * NN) + i0) * DD + h * HDIM;  // uniform

    // ---- Phase 1: thread = one j; f-major hqT -> lane-consecutive loads;
    // each q scalar serves 8 i-rows; hk via SGPR (uniform) loads.
    {
        const int j = t;
        const float* hqb = hqt + (size_t)(b * NH + h) * HDIM * NN;
        f32x2 accu = {0.f, 0.f};
        f32x2 acc[8] = {};
        #pragma unroll
        for (int fc = 0; fc < 16; ++fc) {
            const int fo = fc * 4;
            const float q0 = hqb[(size_t)(fo + 0) * NN + j];
            const float q1 = hqb[(size_t)(fo + 1) * NN + j];
            const float q2 = hqb[(size_t)(fo + 2) * NN + j];
            const float q3 = hqb[(size_t)(fo + 3) * NN + j];
            const float4 a4 = *reinterpret_cast<const float4*>(a + fo);        // uniform
            const f32x2 av[2] = {{a4.x, a4.y}, {a4.z, a4.w}};
            const f32x2 qv[2] = {{q0, q1}, {q2, q3}};
            #pragma unroll
            for (int ii = 0; ii < 8; ++ii) {
                const float4 kv = *reinterpret_cast<const float4*>(hk0 + ii * DD + fo); // uniform
                const f32x2 kk0 = {kv.x, kv.y}, kk1 = {kv.z, kv.w};
                acc[ii] = pk_fma(pk_abs(qv[0] + kk0), av[0], acc[ii]);
                acc[ii] = pk_fma(pk_abs(qv[1] + kk1), av[1], acc[ii]);
            }
            accu = pk_fma(qv[0], av[0], accu);
            accu = pk_fma(qv[1], av[1], accu);
        }
        const float su = 0.6f * (accu.x + accu.y);
        #pragma unroll
        for (int ii = 0; ii < 8; ++ii)
            s[ii][j] = fmaf(0.4f, acc[ii].x + acc[ii].y, su);
    }
    __syncthreads();

    // ---- Phase 2: softmax over j; 8 waves x 8 rows -> 1 row/wave.
    // e-store fused: normalized values written to global straight from
    // registers (saves the separate LDS re-read + store pass).
    {
        const int wv = t >> 6, lane = t & 63;
        float* row = &s[wv][0];
        float vals[8]; float mx = -1e30f;
        #pragma unroll
        for (int k2 = 0; k2 < 8; ++k2) { vals[k2] = row[lane + 64 * k2]; mx = fmaxf(mx, vals[k2]); }
        #pragma unroll
        for (int off = 32; off; off >>= 1) mx = fmaxf(mx, __shfl_xor(mx, off, 64));
        float sum = 0.f;
        #pragma unroll
        for (int k2 = 0; k2 < 8; ++k2) { vals[k2] = __expf(vals[k2] - mx); sum += vals[k2]; }
        #pragma unroll
        for (int off = 32; off; off >>= 1) sum += __shfl_xor(sum, off, 64);
        const float inv = 1.0f / sum;
        float* oe = out_e + (((size_t)(b * NN) + i0 + wv) * NN) * NH + h;
        #pragma unroll
        for (int k2 = 0; k2 < 8; ++k2) {
            const int j = lane + 64 * k2;
            const float p = vals[k2] * inv;
            row[j] = p;
            oe[(size_t)j * NH] = p;               // stride-NH; merges in L2 with
        }                                         // sibling h-blocks (same XCD)
    }
    __syncthreads();

    // ---- Phase 3: wave w owns j in [64w,64w+64); lane = (jsub, 4 cols).
    // Row-major float4 hv loads (each serves 8 i-rows); e via LDS broadcast;
    // jsub reduced in-wave via shfl_xor butterfly.
    {
        const int w    = t >> 6;
        const int lane = t & 63;
        const int jsub = lane >> 4;               // 0..3
        const int c0   = (lane & 15) * 4;         // col quad in h-slice
        const int jbase = w * 64;
        f32x2 acc0[8], acc1[8];
        #pragma unroll
        for (int ii = 0; ii < 8; ++ii) { acc0[ii] = f32x2{0.f, 0.f}; acc1[ii] = f32x2{0.f, 0.f}; }
        const float* hvb = hv + (size_t)(b * NN) * DD + h * HDIM + c0;
        #pragma unroll
        for (int it = 0; it < 16; ++it) {
            const int j = jbase + it * 4 + jsub;
            const float4 v4 = *reinterpret_cast<const float4*>(hvb + (size_t)j * DD);
            const f32x2 v0 = {v4.x, v4.y}, v1 = {v4.z, v4.w};
            #pragma unroll
            for (int ii = 0; ii < 8; ++ii) {
                const float e = s[ii][j];          // LDS broadcast (16 lanes/addr)
                const f32x2 e2 = {e, e};
                acc0[ii] = pk_fma(e2, v0, acc0[ii]);
                acc1[ii] = pk_fma(e2, v1, acc1[ii]);
            }
        }
        // reduce over jsub (lane bits 4,5) in-register
        #pragma unroll
        for (int ii = 0; ii < 8; ++ii) {
            #pragma unroll
            for (int off = 16; off <= 32; off <<= 1) {
                acc0[ii].x += __shfl_xor(acc0[ii].x, off, 64);
                acc0[ii].y += __shfl_xor(acc0[ii].y, off, 64);
                acc1[ii].x += __shfl_xor(acc1[ii].x, off, 64);
                acc1[ii].y += __shfl_xor(acc1[ii].y, off, 64);
            }
        }
        if (lane < 16) {
            #pragma unroll
            for (int ii = 0; ii < 8; ++ii) {
                float4 o; o.x = acc0[ii].x; o.y = acc0[ii].y; o.z = acc1[ii].x; o.w = acc1[ii].y;
                *reinterpret_cast<float4*>(&part[w][ii][c0]) = o;
            }
        }
    }
    __syncthreads();
    {
        const int ii = t >> 6, col = t & 63;      // 512 outputs
        float v = 0.f;
        #pragma unroll
        for (int w = 0; w < 8; ++w) v += part[w][ii][col];
        out_hp[((size_t)(b * NN) + i0 + ii) * DD + h * HDIM + col] = v > 0.f ? v : 0.f;
    }
}

extern "C" void kernel_launch(void* const* d_in, const int* in_sizes, int n_in,
                              void* d_out, int out_size, void* d_ws, size_t ws_size,
                              hipStream_t stream) {
    const float* q   = (const float*)d_in[0];
    const float* kin = (const float*)d_in[1];
    const float* vin = (const float*)d_in[2];
    const float* wq  = (const float*)d_in[3];
    const float* bq  = (const float*)d_in[4];
    const float* wv  = (const float*)d_in[5];
    const float* bv  = (const float*)d_in[6];
    const float* a   = (const float*)d_in[7];

    float* out_hp = (float*)d_out;                    // [B,N,256]
    float* out_e  = out_hp + (size_t)NB * NN * DD;    // [B,N,N,4]

    float* hqt = (float*)d_ws;                        // hqT[b][h][f][j], 1 MB
    float* hk  = hqt + (size_t)NB * NN * DD;
    float* hv  = hk  + (size_t)NB * NN * DD;

    proj_kernel<<<dim3(32, 4, 3), 256, 0, stream>>>(q, kin, vin, wq, bq, wv, bv, hqt, hk, hv);
    attn_kernel<<<dim3(NB * 64 * NH), 512, 0, stream>>>(hqt, hk, hv, a, out_hp, out_e);
}